// Round 9
// baseline (234.715 us; speedup 1.0000x reference)
//
#include <hip/hip_runtime.h>
#include <hip/hip_bf16.h>
#include <stdint.h>

// CrossAttention: B=8, C=256, H=W=64 (N=4096), CR=64.
// proj chain (MFMA): wprep -> transpose(gui) -> projK, projV -> transpose(src) -> projQ
//   Qb/Kb frag-linear for 32x32x16 operands: per 64-px tile [sub<2][dblk<4][lane][8].
//   VF frag-linear: [b][kt][half][cf<4][kblk<4][lane][8] (PV A-operand frags).
// attn: 32x32x16 everywhere. grid 1024 (XCD: b=bid&7), 4 waves = 2q(32) x 2ch(64).
//   S^T = mfma(K,Q) -> lane holds S[q=lane&31][16 keys]; no-max softmax; P stays
//   IN-REGISTER via cvt_pk + v_permlane32_swap (T12) -> PV B-frags, zero P-LDS.
//   V via LDS dbuf (gll16, frag-linear => linear lane*16 reads, conflict-free).

#define B_ 8
#define C_ 256
#define N_ 4096
#define CR_ 64

typedef unsigned short u16;
typedef __attribute__((ext_vector_type(8))) __bf16 bf16x8;
typedef __attribute__((ext_vector_type(4))) float f32x4;
typedef __attribute__((ext_vector_type(16))) float f32x16;

__device__ __forceinline__ u16 f2bf(float f) {
  union { float f; unsigned int u; } v; v.f = f;
  unsigned int r = (v.u + 0x7fffu + ((v.u >> 16) & 1u)) >> 16;
  return (u16)r;
}
__device__ __forceinline__ unsigned int cvtpk(float a, float b) {
  unsigned int r;
  asm("v_cvt_pk_bf16_f32 %0, %1, %2" : "=v"(r) : "v"(a), "v"(b));
  return r;
}

typedef __attribute__((address_space(1))) const unsigned int gu32_t;
typedef __attribute__((address_space(3))) unsigned int lu32_t;
__device__ __forceinline__ void gll16(const void* g, void* l) {
  __builtin_amdgcn_global_load_lds((gu32_t*)g, (lu32_t*)l, 16, 0, 0);
}

// ---------------- Weight prep ----------------
__global__ __launch_bounds__(256) void wprep_kernel(
    const float* __restrict__ Wq, const float* __restrict__ Wk,
    const float* __restrict__ Wv, u16* __restrict__ Wb)
{
  const int i = (blockIdx.x * 256 + threadIdx.x) * 4;
  const int row = i >> 8;
  float4 v;
  float s = 1.0f;
  if (row < 64)       { v = *(const float4*)(Wq + i); s = 1.44269504f; }
  else if (row < 128) { v = *(const float4*)(Wk + i - 64 * 256); }
  else                { v = *(const float4*)(Wv + i - 128 * 256); }
  u16* o = Wb + i;
  o[0] = f2bf(v.x * s); o[1] = f2bf(v.y * s);
  o[2] = f2bf(v.z * s); o[3] = f2bf(v.w * s);
}

// ---------------- Transpose [C][N] f32 -> [N][C] bf16 ----------------------
__global__ __launch_bounds__(256) void transpose_kernel(
    const float* __restrict__ in, u16* __restrict__ outT)
{
  __shared__ u16 Tl[64 * 66];
  const int t = threadIdx.x;
  const int px0 = blockIdx.x * 64, ch0 = blockIdx.y * 64, b = blockIdx.z;
  const float* ip = in + ((size_t)(b * C_ + ch0)) * N_ + px0;
  const int cx = t >> 4, p4 = (t & 15) * 4;
#pragma unroll
  for (int p = 0; p < 4; ++p) {
    const int ch = cx + p * 16;
    float4 v = *(const float4*)(ip + (size_t)ch * N_ + p4);
    Tl[(p4 + 0) * 66 + ch] = f2bf(v.x);
    Tl[(p4 + 1) * 66 + ch] = f2bf(v.y);
    Tl[(p4 + 2) * 66 + ch] = f2bf(v.z);
    Tl[(p4 + 3) * 66 + ch] = f2bf(v.w);
  }
  __syncthreads();
  const int row = t >> 3, seg = t & 7;
  u16* op = outT + ((size_t)(b * N_) + px0) * C_ + ch0 + seg * 8;
#pragma unroll
  for (int p = 0; p < 2; ++p) {
    const int r2 = row + p * 32;
    *(uint4*)(op + (size_t)r2 * C_) = *(const uint4*)(&Tl[r2 * 66 + seg * 8]);
  }
}

// ---------------- Q/K projection (MFMA), 32x32-frag-linear output ----------
// Output per 64-px tile tt: [sub<2][dblk<4][lane<64][8] bf16; value =
//   X[px = tt*64 + sub*32 + (lane&31)][d = dblk*16 + (lane>>5)*8 + j].
__global__ __launch_bounds__(128) void projqk_kernel(
    const u16* __restrict__ inT, const u16* __restrict__ W64, u16* __restrict__ dst)
{
  __shared__ u16 Tl[2 * 64 * 72];
  const int t = threadIdx.x, lane = t & 63, wave = t >> 6;
  const int lg = lane >> 4, lm = lane & 15;
  const int b = blockIdx.y;
  const int px0 = blockIdx.x * 128 + wave * 64;
  const u16* ib = inT + ((size_t)(b * N_) + px0) * C_;

  f32x4 acc[4][4];
  const f32x4 z4 = {0.f, 0.f, 0.f, 0.f};
#pragma unroll
  for (int i = 0; i < 4; ++i)
#pragma unroll
    for (int j = 0; j < 4; ++j) acc[i][j] = z4;

  for (int ks = 0; ks < 8; ++ks) {
    bf16x8 wf[4], pf[4];
#pragma unroll
    for (int mi = 0; mi < 4; ++mi)
      wf[mi] = *(const bf16x8*)(W64 + (mi * 16 + lm) * C_ + ks * 32 + lg * 8);
#pragma unroll
    for (int ni = 0; ni < 4; ++ni)
      pf[ni] = *(const bf16x8*)(ib + (size_t)(ni * 16 + lm) * C_ + ks * 32 + lg * 8);
#pragma unroll
    for (int mi = 0; mi < 4; ++mi)
#pragma unroll
      for (int ni = 0; ni < 4; ++ni)
        acc[mi][ni] = __builtin_amdgcn_mfma_f32_16x16x32_bf16(wf[mi], pf[ni], acc[mi][ni], 0, 0, 0);
  }

  // D[d][px] -> Tl[px][d] (stride 72 u16, 16B-aligned rows)
  u16* tw = Tl + wave * 64 * 72;
#pragma unroll
  for (int mi = 0; mi < 4; ++mi)
#pragma unroll
    for (int ni = 0; ni < 4; ++ni)
#pragma unroll
      for (int rp = 0; rp < 2; ++rp)
        *(unsigned int*)&tw[(ni * 16 + lm) * 72 + mi * 16 + lg * 4 + rp * 2] =
            cvtpk(acc[mi][ni][rp * 2], acc[mi][ni][rp * 2 + 1]);

  const int l31 = lane & 31, hi2 = lane >> 5;
  const int tt = b * 64 + blockIdx.x * 2 + wave;
  u16* op = dst + (size_t)tt * 4096 + lane * 8;
#pragma unroll
  for (int sub = 0; sub < 2; ++sub)
#pragma unroll
    for (int db = 0; db < 4; ++db)
      *(uint4*)(op + (sub * 4 + db) * 512) =
          *(const uint4*)(&tw[(sub * 32 + l31) * 72 + db * 16 + hi2 * 8]);
}

// ---------------- V projection (MFMA) -> VF 32x32-frag-linear --------------
// VF[b][kt][half][cf<4][kblk<4][lane<64][8]; value =
//   V[ch = half*128 + cf*32 + (lane&31)][key = kt*64 + kblk*16 + (lane>>5)*8 + j].
__global__ __launch_bounds__(128) void projv_kernel(
    const u16* __restrict__ inT, const u16* __restrict__ Wv256,
    const float* __restrict__ bv, u16* __restrict__ VF)
{
  __shared__ u16 Tl[2 * 64 * 72];
  const int t = threadIdx.x, lane = t & 63, wave = t >> 6;
  const int lg = lane >> 4, lm = lane & 15;
  const int b = blockIdx.y;
  const int half = blockIdx.z;
  const int px0 = blockIdx.x * 128;
  const int chb = half * 128 + wave * 64;
  const u16* ib = inT + ((size_t)(b * N_) + px0) * C_;
  const u16* wb = Wv256 + (size_t)chb * C_;
  u16* tw = Tl + wave * 64 * 72;
  const int l31 = lane & 31, hi2 = lane >> 5;

  f32x4 bq[4];
#pragma unroll
  for (int mi = 0; mi < 4; ++mi)
    bq[mi] = *(const f32x4*)(bv + chb + mi * 16 + lg * 4);

  const f32x4 z4 = {0.f, 0.f, 0.f, 0.f};
  for (int pg = 0; pg < 2; ++pg) {
    f32x4 acc[4][4];
#pragma unroll
    for (int i = 0; i < 4; ++i)
#pragma unroll
      for (int j = 0; j < 4; ++j) acc[i][j] = z4;
    for (int ks = 0; ks < 8; ++ks) {
      bf16x8 wf[4], pf[4];
#pragma unroll
      for (int mi = 0; mi < 4; ++mi)
        wf[mi] = *(const bf16x8*)(wb + (mi * 16 + lm) * C_ + ks * 32 + lg * 8);
#pragma unroll
      for (int ni = 0; ni < 4; ++ni)
        pf[ni] = *(const bf16x8*)(ib + (size_t)(pg * 64 + ni * 16 + lm) * C_ + ks * 32 + lg * 8);
#pragma unroll
      for (int mi = 0; mi < 4; ++mi)
#pragma unroll
        for (int ni = 0; ni < 4; ++ni)
          acc[mi][ni] = __builtin_amdgcn_mfma_f32_16x16x32_bf16(wf[mi], pf[ni], acc[mi][ni], 0, 0, 0);
    }
    // D[ch][key] -> tw[ch_local][key] (wave-local)
#pragma unroll
    for (int mi = 0; mi < 4; ++mi)
#pragma unroll
      for (int ni = 0; ni < 4; ++ni)
#pragma unroll
        for (int r = 0; r < 4; ++r)
          tw[(mi * 16 + lg * 4 + r) * 72 + ni * 16 + lm] = f2bf(acc[mi][ni][r] + bq[mi][r]);
    // emit frags (cf_in_half = wave*2 + c2)
    const int kt = blockIdx.x * 2 + pg;
    u16* vo = VF + (((size_t)(b * 64 + kt)) * 2 + half) * 8192;
#pragma unroll
    for (int c2 = 0; c2 < 2; ++c2)
#pragma unroll
      for (int kblk = 0; kblk < 4; ++kblk)
        *(uint4*)(vo + ((wave * 2 + c2) * 4 + kblk) * 512 + lane * 8) =
            *(const uint4*)(&tw[(c2 * 32 + l31) * 72 + kblk * 16 + hi2 * 8]);
  }
}

// ---------------- Flash attention (32x32, in-register P) ----------------
// LDS: Vbuf0 [0,16384), Vbuf1 [16384,32768).
#define VB1 16384

__global__ __launch_bounds__(256, 3) void attn_kernel(
    const u16* __restrict__ Qb, const u16* __restrict__ Kb, const u16* __restrict__ VF,
    const float* __restrict__ source, const float* __restrict__ gamma,
    float* __restrict__ out)
{
  __shared__ uint4 smem4[2048];  // 32768 B
  char* smem = (char*)smem4;

  const int bid = blockIdx.x;
  const int b = bid & 7;              // XCD-local batch
  const int idx = bid >> 3;
  const int qt = idx & 63;
  const int half = idx >> 6;

  const int t = threadIdx.x;
  const int lane = t & 63;
  const int wave = t >> 6;
  const int qw = wave & 1;            // 32-q slice
  const int wc = wave >> 1;           // 64-ch slice
  const int l31 = lane & 31;
  const int hi = lane >> 5;
  const int q0 = qt * 64;

  // Q frags: B-operand, col=q=l31, k=d = db*16 + hi*8 + j
  bf16x8 aq[4];
  {
    const u16* qp = Qb + ((size_t)(b * 64 + qt)) * 4096 + (qw * 4) * 512 + lane * 8;
#pragma unroll
    for (int db = 0; db < 4; ++db) aq[db] = *(const bf16x8*)(qp + db * 512);
  }

  const u16* KbT = Kb + (size_t)b * (64 * 4096);
  const char* VFb = (const char*)VF + ((size_t)(b * 128 + half)) * 16384;

  f32x16 acc[2];
#pragma unroll
  for (int c2 = 0; c2 < 2; ++c2)
#pragma unroll
    for (int r = 0; r < 16; ++r) acc[c2][r] = 0.f;
  float mrow = 0.f, lrow = 0.f;

  bf16x8 kC[8];

#define STAGEV(KTILE, VOFF) do {                                             \
    const char* vs_ = VFb + (size_t)(KTILE) * 32768 + t * 16;                \
    _Pragma("unroll")                                                        \
    for (int i = 0; i < 4; ++i)                                              \
      gll16(vs_ + i * 4096, smem + (VOFF) + wave * 1024 + i * 4096);         \
  } while (0)

#define LOADK(KT) do {                                                       \
    const u16* kp_ = KbT + (size_t)(KT) * 4096 + lane * 8;                   \
    _Pragma("unroll")                                                        \
    for (int f = 0; f < 8; ++f)                                              \
      kC[f] = *(const bf16x8*)(kp_ + f * 512);                               \
  } while (0)

// Iter T: barrier (V(T) staged; K(T) in regs) -> stage V(T+1) -> S^T MFMAs
// (32x32x16, A=K frag, B=Q frag) -> prefetch K(T+1) -> no-max softmax ->
// P B-frags in-register (cvt_pk + permlane32_swap) -> PV from LDS V-frags.
#define ITER(KT, VCUR, VNXT) do {                                            \
    __syncthreads();                                                         \
    const int ktn_ = ((KT) + 1 < 64) ? (KT) + 1 : 63;                        \
    STAGEV(ktn_, VNXT);                                                      \
    f32x16 sf[2];                                                            \
    __builtin_amdgcn_s_setprio(1);                                           \
    _Pragma("unroll")                                                        \
    for (int kb = 0; kb < 2; ++kb) {                                         \
      _Pragma("unroll")                                                      \
      for (int r = 0; r < 16; ++r) sf[kb][r] = 0.f;                          \
      _Pragma("unroll")                                                      \
      for (int db = 0; db < 4; ++db)                                         \
        sf[kb] = __builtin_amdgcn_mfma_f32_32x32x16_bf16(                    \
            kC[kb * 4 + db], aq[db], sf[kb], 0, 0, 0);                       \
    }                                                                        \
    __builtin_amdgcn_s_setprio(0);                                           \
    LOADK(ktn_);                                                             \
    float s_ = 0.f;                                                          \
    _Pragma("unroll")                                                        \
    for (int kb = 0; kb < 2; ++kb)                                           \
      _Pragma("unroll")                                                      \
      for (int r = 0; r < 16; ++r) {                                         \
        float e_ = __builtin_amdgcn_exp2f(sf[kb][r] - mrow);                 \
        sf[kb][r] = e_;                                                      \
        s_ += e_;                                                            \
      }                                                                      \
    float xs_ = s_, ys_ = s_;                                                \
    asm("v_permlane32_swap_b32 %0, %1" : "+v"(xs_), "+v"(ys_));              \
    lrow += xs_ + ys_;                                                       \
    if (lrow > 1e30f) {  /* robustness guard */                              \
      const float dsc_ = 5.421010862e-20f;  /* 2^-64 */                      \
      lrow *= dsc_; mrow += 64.f;                                            \
      _Pragma("unroll")                                                      \
      for (int c2 = 0; c2 < 2; ++c2)                                         \
        _Pragma("unroll")                                                    \
        for (int r = 0; r < 16; ++r) acc[c2][r] *= dsc_;                     \
    }                                                                        \
    _Pragma("unroll")                                                        \
    for (int kblk = 0; kblk < 4; ++kblk) {                                   \
      const int kbi_ = kblk >> 1, o_ = (kblk & 1) * 8;                       \
      unsigned uA_ = cvtpk(sf[kbi_][o_ + 0], sf[kbi_][o_ + 1]);              \
      unsigned vA_ = cvtpk(sf[kbi_][o_ + 2], sf[kbi_][o_ + 3]);              \
      unsigned uB_ = cvtpk(sf[kbi_][o_ + 4], sf[kbi_][o_ + 5]);              \
      unsigned vB_ = cvtpk(sf[kbi_][o_ + 6], sf[kbi_][o_ + 7]);              \
      asm("v_permlane32_swap_b32 %0, %1" : "+v"(uA_), "+v"(uB_));            \
      asm("v_permlane32_swap_b32 %0, %1" : "+v"(vA_), "+v"(vB_));            \
      uint4 pw_; pw_.x = uA_; pw_.y = vA_; pw_.z = uB_; pw_.w = vB_;         \
      bf16x8 pf_; __builtin_memcpy(&pf_, &pw_, 16);                          \
      __builtin_amdgcn_s_setprio(1);                                         \
      _Pragma("unroll")                                                      \
      for (int c2 = 0; c2 < 2; ++c2) {                                       \
        bf16x8 vf_ = *(const bf16x8*)(smem + (VCUR) +                        \
            (((wc * 2 + c2) * 4 + kblk) << 10) + lane * 16);                 \
        acc[c2] = __builtin_amdgcn_mfma_f32_32x32x16_bf16(vf_, pf_, acc[c2], 0, 0, 0); \
      }                                                                      \
      __builtin_amdgcn_s_setprio(0);                                         \
    }                                                                        \
  } while (0)

  // prologue
  STAGEV(0, 0);
  LOADK(0);
  for (int kt2 = 0; kt2 < 64; kt2 += 2) {
    ITER(kt2,     0,   VB1);
    ITER(kt2 + 1, VB1, 0);
  }
  asm volatile("s_waitcnt vmcnt(0)" ::: "memory");  // drain trailing LDS-DMA

  // ---- epilogue: D[ch][q]: ch-row = (r&3)+8*(r>>2)+4*hi, q = l31 ----
  const float inv = gamma[0] / fmaxf(lrow, 1e-37f);
#pragma unroll
  for (int c2 = 0; c2 < 2; ++c2)
#pragma unroll
    for (int r = 0; r < 16; ++r) {
      const int ch = half * 128 + wc * 64 + c2 * 32 + (r & 3) + 8 * (r >> 2) + 4 * hi;
      size_t gi = ((size_t)(b * C_ + ch)) * N_ + q0 + qw * 32 + l31;
      out[gi] = acc[c2][r] * inv + source[gi];
    }
}

extern "C" void kernel_launch(void* const* d_in, const int* in_sizes, int n_in,
                              void* d_out, int out_size, void* d_ws, size_t ws_size,
                              hipStream_t stream) {
  const float* src = (const float*)d_in[0];
  const float* gui = (const float*)d_in[1];
  const float* Wq  = (const float*)d_in[2];
  const float* Wk  = (const float*)d_in[3];
  const float* Wv  = (const float*)d_in[4];
  const float* bv  = (const float*)d_in[5];
  const float* gm  = (const float*)d_in[6];
  float* out = (float*)d_out;

  u16* Qb = (u16*)d_ws;                         // 4 MB
  u16* Kb = Qb + (size_t)B_ * N_ * CR_;         // 4 MB
  u16* VF = Kb + (size_t)B_ * N_ * CR_;         // 16 MB (ws total 24 MB)

  u16* inT = (u16*)d_out;                       // 16 MB scratch inside d_out
  u16* Wb  = inT + (size_t)B_ * N_ * C_;        // 288 KB

  wprep_kernel<<<dim3(144), dim3(256), 0, stream>>>(Wq, Wk, Wv, Wb);
  transpose_kernel<<<dim3(64, 4, B_), dim3(256), 0, stream>>>(gui, inT);
  projqk_kernel<<<dim3(32, B_), dim3(128), 0, stream>>>(inT, Wb + 64 * 256, Kb);
  projv_kernel<<<dim3(32, B_, 2), dim3(128), 0, stream>>>(inT, Wb + 128 * 256, bv, VF);
  transpose_kernel<<<dim3(64, 4, B_), dim3(256), 0, stream>>>(src, inT);
  projqk_kernel<<<dim3(32, B_), dim3(128), 0, stream>>>(inT, Wb, Qb);

  attn_kernel<<<dim3(1024), dim3(256), 0, stream>>>(Qb, Kb, VF, src, gm, out);
}

// Round 10
// 223.538 us; speedup vs baseline: 1.0500x; 1.0500x over previous
//
#include <hip/hip_runtime.h>
#include <hip/hip_bf16.h>
#include <stdint.h>

// CrossAttention: B=8, C=256, H=W=64 (N=4096), CR=64.
// proj chain (MFMA): wprep -> transpose(gui) -> projK, projV -> transpose(src) -> projQ
//   Qb/Kb frag-linear for 32x32x16 operands: per 64-px tile [sub<2][dblk<4][lane][8].
//   VF frag-linear: [b][kt][half][cf<4][kblk<4][lane][8] (PV A-operand frags).
// attn: 32x32x16. grid 1024 (XCD: b=bid&7), 4 waves = 2q(32) x 2ch(64), 4 blk/CU.
//   S^T = mfma(K,Q); no-max softmax; P in-register (cvt_pk + permlane32_swap);
//   V via LDS dbuf (gll16, frag-linear, 0 conflicts). S processed per 32-key half
//   (sf single f32x16) to fit 4 waves/SIMD (<=128 unified VGPR+AGPR).

#define B_ 8
#define C_ 256
#define N_ 4096
#define CR_ 64

typedef unsigned short u16;
typedef __attribute__((ext_vector_type(8))) __bf16 bf16x8;
typedef __attribute__((ext_vector_type(4))) float f32x4;
typedef __attribute__((ext_vector_type(16))) float f32x16;

__device__ __forceinline__ u16 f2bf(float f) {
  union { float f; unsigned int u; } v; v.f = f;
  unsigned int r = (v.u + 0x7fffu + ((v.u >> 16) & 1u)) >> 16;
  return (u16)r;
}
__device__ __forceinline__ unsigned int cvtpk(float a, float b) {
  unsigned int r;
  asm("v_cvt_pk_bf16_f32 %0, %1, %2" : "=v"(r) : "v"(a), "v"(b));
  return r;
}

typedef __attribute__((address_space(1))) const unsigned int gu32_t;
typedef __attribute__((address_space(3))) unsigned int lu32_t;
__device__ __forceinline__ void gll16(const void* g, void* l) {
  __builtin_amdgcn_global_load_lds((gu32_t*)g, (lu32_t*)l, 16, 0, 0);
}

// ---------------- Weight prep ----------------
__global__ __launch_bounds__(256) void wprep_kernel(
    const float* __restrict__ Wq, const float* __restrict__ Wk,
    const float* __restrict__ Wv, u16* __restrict__ Wb)
{
  const int i = (blockIdx.x * 256 + threadIdx.x) * 4;
  const int row = i >> 8;
  float4 v;
  float s = 1.0f;
  if (row < 64)       { v = *(const float4*)(Wq + i); s = 1.44269504f; }
  else if (row < 128) { v = *(const float4*)(Wk + i - 64 * 256); }
  else                { v = *(const float4*)(Wv + i - 128 * 256); }
  u16* o = Wb + i;
  o[0] = f2bf(v.x * s); o[1] = f2bf(v.y * s);
  o[2] = f2bf(v.z * s); o[3] = f2bf(v.w * s);
}

// ---------------- Transpose [C][N] f32 -> [N][C] bf16 ----------------------
__global__ __launch_bounds__(256) void transpose_kernel(
    const float* __restrict__ in, u16* __restrict__ outT)
{
  __shared__ u16 Tl[64 * 66];
  const int t = threadIdx.x;
  const int px0 = blockIdx.x * 64, ch0 = blockIdx.y * 64, b = blockIdx.z;
  const float* ip = in + ((size_t)(b * C_ + ch0)) * N_ + px0;
  const int cx = t >> 4, p4 = (t & 15) * 4;
#pragma unroll
  for (int p = 0; p < 4; ++p) {
    const int ch = cx + p * 16;
    float4 v = *(const float4*)(ip + (size_t)ch * N_ + p4);
    Tl[(p4 + 0) * 66 + ch] = f2bf(v.x);
    Tl[(p4 + 1) * 66 + ch] = f2bf(v.y);
    Tl[(p4 + 2) * 66 + ch] = f2bf(v.z);
    Tl[(p4 + 3) * 66 + ch] = f2bf(v.w);
  }
  __syncthreads();
  const int row = t >> 3, seg = t & 7;
  u16* op = outT + ((size_t)(b * N_) + px0) * C_ + ch0 + seg * 8;
#pragma unroll
  for (int p = 0; p < 2; ++p) {
    const int r2 = row + p * 32;
    *(uint4*)(op + (size_t)r2 * C_) = *(const uint4*)(&Tl[r2 * 66 + seg * 8]);
  }
}

// ---------------- Q/K projection (MFMA), 32x32-frag-linear output ----------
// Output per 64-px tile tt: [sub<2][dblk<4][lane<64][8] bf16; value =
//   X[px = tt*64 + sub*32 + (lane&31)][d = dblk*16 + (lane>>5)*8 + j].
__global__ __launch_bounds__(128) void projqk_kernel(
    const u16* __restrict__ inT, const u16* __restrict__ W64, u16* __restrict__ dst)
{
  __shared__ u16 Tl[2 * 64 * 72];
  const int t = threadIdx.x, lane = t & 63, wave = t >> 6;
  const int lg = lane >> 4, lm = lane & 15;
  const int b = blockIdx.y;
  const int px0 = blockIdx.x * 128 + wave * 64;
  const u16* ib = inT + ((size_t)(b * N_) + px0) * C_;

  f32x4 acc[4][4];
  const f32x4 z4 = {0.f, 0.f, 0.f, 0.f};
#pragma unroll
  for (int i = 0; i < 4; ++i)
#pragma unroll
    for (int j = 0; j < 4; ++j) acc[i][j] = z4;

  for (int ks = 0; ks < 8; ++ks) {
    bf16x8 wf[4], pf[4];
#pragma unroll
    for (int mi = 0; mi < 4; ++mi)
      wf[mi] = *(const bf16x8*)(W64 + (mi * 16 + lm) * C_ + ks * 32 + lg * 8);
#pragma unroll
    for (int ni = 0; ni < 4; ++ni)
      pf[ni] = *(const bf16x8*)(ib + (size_t)(ni * 16 + lm) * C_ + ks * 32 + lg * 8);
#pragma unroll
    for (int mi = 0; mi < 4; ++mi)
#pragma unroll
      for (int ni = 0; ni < 4; ++ni)
        acc[mi][ni] = __builtin_amdgcn_mfma_f32_16x16x32_bf16(wf[mi], pf[ni], acc[mi][ni], 0, 0, 0);
  }

  // D[d][px] -> Tl[px][d] (stride 72 u16, 16B-aligned rows)
  u16* tw = Tl + wave * 64 * 72;
#pragma unroll
  for (int mi = 0; mi < 4; ++mi)
#pragma unroll
    for (int ni = 0; ni < 4; ++ni)
#pragma unroll
      for (int rp = 0; rp < 2; ++rp)
        *(unsigned int*)&tw[(ni * 16 + lm) * 72 + mi * 16 + lg * 4 + rp * 2] =
            cvtpk(acc[mi][ni][rp * 2], acc[mi][ni][rp * 2 + 1]);

  const int l31 = lane & 31, hi2 = lane >> 5;
  const int tt = b * 64 + blockIdx.x * 2 + wave;
  u16* op = dst + (size_t)tt * 4096 + lane * 8;
#pragma unroll
  for (int sub = 0; sub < 2; ++sub)
#pragma unroll
    for (int db = 0; db < 4; ++db)
      *(uint4*)(op + (sub * 4 + db) * 512) =
          *(const uint4*)(&tw[(sub * 32 + l31) * 72 + db * 16 + hi2 * 8]);
}

// ---------------- V projection (MFMA) -> VF 32x32-frag-linear --------------
// VF[b][kt][half][cf<4][kblk<4][lane<64][8]; value =
//   V[ch = half*128 + cf*32 + (lane&31)][key = kt*64 + kblk*16 + (lane>>5)*8 + j].
__global__ __launch_bounds__(128) void projv_kernel(
    const u16* __restrict__ inT, const u16* __restrict__ Wv256,
    const float* __restrict__ bv, u16* __restrict__ VF)
{
  __shared__ u16 Tl[2 * 64 * 72];
  const int t = threadIdx.x, lane = t & 63, wave = t >> 6;
  const int lg = lane >> 4, lm = lane & 15;
  const int b = blockIdx.y;
  const int half = blockIdx.z;
  const int px0 = blockIdx.x * 128;
  const int chb = half * 128 + wave * 64;
  const u16* ib = inT + ((size_t)(b * N_) + px0) * C_;
  const u16* wb = Wv256 + (size_t)chb * C_;
  u16* tw = Tl + wave * 64 * 72;
  const int l31 = lane & 31, hi2 = lane >> 5;

  f32x4 bq[4];
#pragma unroll
  for (int mi = 0; mi < 4; ++mi)
    bq[mi] = *(const f32x4*)(bv + chb + mi * 16 + lg * 4);

  const f32x4 z4 = {0.f, 0.f, 0.f, 0.f};
  for (int pg = 0; pg < 2; ++pg) {
    f32x4 acc[4][4];
#pragma unroll
    for (int i = 0; i < 4; ++i)
#pragma unroll
      for (int j = 0; j < 4; ++j) acc[i][j] = z4;
    for (int ks = 0; ks < 8; ++ks) {
      bf16x8 wf[4], pf[4];
#pragma unroll
      for (int mi = 0; mi < 4; ++mi)
        wf[mi] = *(const bf16x8*)(wb + (mi * 16 + lm) * C_ + ks * 32 + lg * 8);
#pragma unroll
      for (int ni = 0; ni < 4; ++ni)
        pf[ni] = *(const bf16x8*)(ib + (size_t)(pg * 64 + ni * 16 + lm) * C_ + ks * 32 + lg * 8);
#pragma unroll
      for (int mi = 0; mi < 4; ++mi)
#pragma unroll
        for (int ni = 0; ni < 4; ++ni)
          acc[mi][ni] = __builtin_amdgcn_mfma_f32_16x16x32_bf16(wf[mi], pf[ni], acc[mi][ni], 0, 0, 0);
    }
    // D[ch][key] -> tw[ch_local][key] (wave-local)
#pragma unroll
    for (int mi = 0; mi < 4; ++mi)
#pragma unroll
      for (int ni = 0; ni < 4; ++ni)
#pragma unroll
        for (int r = 0; r < 4; ++r)
          tw[(mi * 16 + lg * 4 + r) * 72 + ni * 16 + lm] = f2bf(acc[mi][ni][r] + bq[mi][r]);
    // emit frags (cf_in_half = wave*2 + c2)
    const int kt = blockIdx.x * 2 + pg;
    u16* vo = VF + (((size_t)(b * 64 + kt)) * 2 + half) * 8192;
#pragma unroll
    for (int c2 = 0; c2 < 2; ++c2)
#pragma unroll
      for (int kblk = 0; kblk < 4; ++kblk)
        *(uint4*)(vo + ((wave * 2 + c2) * 4 + kblk) * 512 + lane * 8) =
            *(const uint4*)(&tw[(c2 * 32 + l31) * 72 + kblk * 16 + hi2 * 8]);
  }
}

// ---------------- Flash attention (32x32, in-register P, half-staged S) ----
// LDS: Vbuf0 [0,16384), Vbuf1 [16384,32768).
#define VB1 16384

__global__ __launch_bounds__(256, 4) void attn_kernel(
    const u16* __restrict__ Qb, const u16* __restrict__ Kb, const u16* __restrict__ VF,
    const float* __restrict__ source, const float* __restrict__ gamma,
    float* __restrict__ out)
{
  __shared__ uint4 smem4[2048];  // 32768 B
  char* smem = (char*)smem4;

  const int bid = blockIdx.x;
  const int b = bid & 7;              // XCD-local batch
  const int idx = bid >> 3;
  const int qt = idx & 63;
  const int half = idx >> 6;

  const int t = threadIdx.x;
  const int lane = t & 63;
  const int wave = t >> 6;
  const int qw = wave & 1;            // 32-q slice
  const int wc = wave >> 1;           // 64-ch slice
  const int l31 = lane & 31;
  const int hi = lane >> 5;
  const int q0 = qt * 64;

  // Q frags: B-operand, col=q=l31, k=d = db*16 + hi*8 + j
  bf16x8 aq[4];
  {
    const u16* qp = Qb + ((size_t)(b * 64 + qt)) * 4096 + (qw * 4) * 512 + lane * 8;
#pragma unroll
    for (int db = 0; db < 4; ++db) aq[db] = *(const bf16x8*)(qp + db * 512);
  }

  const u16* KbT = Kb + (size_t)b * (64 * 4096);
  const char* VFb = (const char*)VF + ((size_t)(b * 128 + half)) * 16384;

  f32x16 acc[2];
#pragma unroll
  for (int c2 = 0; c2 < 2; ++c2)
#pragma unroll
    for (int r = 0; r < 16; ++r) acc[c2][r] = 0.f;
  float mrow = 0.f, lrow = 0.f;

  bf16x8 kC[8];

#define STAGEV(KTILE, VOFF) do {                                             \
    const char* vs_ = VFb + (size_t)(KTILE) * 32768 + t * 16;                \
    _Pragma("unroll")                                                        \
    for (int i = 0; i < 4; ++i)                                              \
      gll16(vs_ + i * 4096, smem + (VOFF) + wave * 1024 + i * 4096);         \
  } while (0)

#define LOADK_H(KT, H) do {                                                  \
    const u16* kp_ = KbT + (size_t)(KT) * 4096 + (H) * 2048 + lane * 8;      \
    _Pragma("unroll")                                                        \
    for (int f = 0; f < 4; ++f)                                              \
      kC[(H) * 4 + f] = *(const bf16x8*)(kp_ + f * 512);                     \
  } while (0)

// One PV pair for key-block KBLK, P packed transiently from SF (offset O8).
#define PVPAIR(SF, KBLK, O8, VCUR) do {                                      \
    unsigned uA_ = cvtpk(SF[(O8) + 0], SF[(O8) + 1]);                        \
    unsigned vA_ = cvtpk(SF[(O8) + 2], SF[(O8) + 3]);                        \
    unsigned uB_ = cvtpk(SF[(O8) + 4], SF[(O8) + 5]);                        \
    unsigned vB_ = cvtpk(SF[(O8) + 6], SF[(O8) + 7]);                        \
    asm("v_permlane32_swap_b32 %0, %1" : "+v"(uA_), "+v"(uB_));              \
    asm("v_permlane32_swap_b32 %0, %1" : "+v"(vA_), "+v"(vB_));              \
    uint4 pw_; pw_.x = uA_; pw_.y = vA_; pw_.z = uB_; pw_.w = vB_;           \
    bf16x8 pf_; __builtin_memcpy(&pf_, &pw_, 16);                            \
    __builtin_amdgcn_s_setprio(1);                                           \
    _Pragma("unroll")                                                        \
    for (int c2 = 0; c2 < 2; ++c2) {                                         \
      bf16x8 vf_ = *(const bf16x8*)(smem + (VCUR) +                          \
          (((wc * 2 + c2) * 4 + (KBLK)) << 10) + lane * 16);                 \
      acc[c2] = __builtin_amdgcn_mfma_f32_32x32x16_bf16(vf_, pf_, acc[c2], 0, 0, 0); \
    }                                                                        \
    __builtin_amdgcn_s_setprio(0);                                           \
  } while (0)

// Iter T (single barrier): barrier (V(T) staged) -> stage V(T+1) -> per 32-key
// half kb: {S-MFMA(kb) -> refill kC half -> exp -> PV pair x2} -> l update.
#define ITER(KT, VCUR, VNXT) do {                                            \
    __syncthreads();                                                         \
    const int ktn_ = (KT) + 1;                                               \
    const bool pf_ = ktn_ < 64;                                              \
    if (pf_) STAGEV(ktn_, VNXT);                                             \
    float s_ = 0.f;                                                          \
    /* ---- key-half 0 ---- */                                               \
    {                                                                        \
      f32x16 sf;                                                             \
      _Pragma("unroll")                                                      \
      for (int r = 0; r < 16; ++r) sf[r] = 0.f;                              \
      __builtin_amdgcn_s_setprio(1);                                         \
      _Pragma("unroll")                                                      \
      for (int db = 0; db < 4; ++db)                                         \
        sf = __builtin_amdgcn_mfma_f32_32x32x16_bf16(kC[db], aq[db], sf, 0, 0, 0); \
      __builtin_amdgcn_s_setprio(0);                                         \
      if (pf_) LOADK_H(ktn_, 0);                                             \
      _Pragma("unroll")                                                      \
      for (int r = 0; r < 16; ++r) {                                         \
        float e_ = __builtin_amdgcn_exp2f(sf[r] - mrow);                     \
        sf[r] = e_;                                                          \
        s_ += e_;                                                            \
      }                                                                      \
      PVPAIR(sf, 0, 0, VCUR);                                                \
      PVPAIR(sf, 1, 8, VCUR);                                                \
    }                                                                        \
    /* ---- key-half 1 ---- */                                               \
    {                                                                        \
      f32x16 sg;                                                             \
      _Pragma("unroll")                                                      \
      for (int r = 0; r < 16; ++r) sg[r] = 0.f;                              \
      __builtin_amdgcn_s_setprio(1);                                         \
      _Pragma("unroll")                                                      \
      for (int db = 0; db < 4; ++db)                                         \
        sg = __builtin_amdgcn_mfma_f32_32x32x16_bf16(kC[4 + db], aq[db], sg, 0, 0, 0); \
      __builtin_amdgcn_s_setprio(0);                                         \
      if (pf_) LOADK_H(ktn_, 1);                                             \
      _Pragma("unroll")                                                      \
      for (int r = 0; r < 16; ++r) {                                         \
        float e_ = __builtin_amdgcn_exp2f(sg[r] - mrow);                     \
        sg[r] = e_;                                                          \
        s_ += e_;                                                            \
      }                                                                      \
      PVPAIR(sg, 2, 0, VCUR);                                                \
      PVPAIR(sg, 3, 8, VCUR);                                                \
    }                                                                        \
    float xs_ = s_, ys_ = s_;                                                \
    asm("v_permlane32_swap_b32 %0, %1" : "+v"(xs_), "+v"(ys_));              \
    lrow += xs_ + ys_;                                                       \
    if (lrow > 1e30f) {  /* robustness guard */                              \
      const float dsc_ = 5.421010862e-20f;  /* 2^-64 */                      \
      lrow *= dsc_; mrow += 64.f;                                            \
      _Pragma("unroll")                                                      \
      for (int c2 = 0; c2 < 2; ++c2)                                         \
        _Pragma("unroll")                                                    \
        for (int r = 0; r < 16; ++r) acc[c2][r] *= dsc_;                     \
    }                                                                        \
  } while (0)

  // prologue
  STAGEV(0, 0);
  LOADK_H(0, 0);
  LOADK_H(0, 1);
  for (int kt2 = 0; kt2 < 64; kt2 += 2) {
    ITER(kt2,     0,   VB1);
    ITER(kt2 + 1, VB1, 0);
  }
  asm volatile("s_waitcnt vmcnt(0)" ::: "memory");  // drain trailing LDS-DMA

  // ---- epilogue: D[ch][q]: ch-row = (r&3)+8*(r>>2)+4*hi, q = l31 ----
  const float inv = gamma[0] / fmaxf(lrow, 1e-37f);
#pragma unroll
  for (int c2 = 0; c2 < 2; ++c2)
#pragma unroll
    for (int r = 0; r < 16; ++r) {
      const int ch = half * 128 + wc * 64 + c2 * 32 + (r & 3) + 8 * (r >> 2) + 4 * hi;
      size_t gi = ((size_t)(b * C_ + ch)) * N_ + q0 + qw * 32 + l31;
      out[gi] = acc[c2][r] * inv + source[gi];
    }
}

extern "C" void kernel_launch(void* const* d_in, const int* in_sizes, int n_in,
                              void* d_out, int out_size, void* d_ws, size_t ws_size,
                              hipStream_t stream) {
  const float* src = (const float*)d_in[0];
  const float* gui = (const float*)d_in[1];
  const float* Wq  = (const float*)d_in[2];
  const float* Wk  = (const float*)d_in[3];
  const float* Wv  = (const float*)d_in[4];
  const float* bv  = (const float*)d_in[5];
  const float* gm  = (const float*)d_in[6];
  float* out = (float*)d_out;

  u16* Qb = (u16*)d_ws;                         // 4 MB
  u16* Kb = Qb + (size_t)B_ * N_ * CR_;         // 4 MB
  u16* VF = Kb + (size_t)B_ * N_ * CR_;         // 16 MB (ws total 24 MB)

  u16* inT = (u16*)d_out;                       // 16 MB scratch inside d_out
  u16* Wb  = inT + (size_t)B_ * N_ * C_;        // 288 KB

  wprep_kernel<<<dim3(144), dim3(256), 0, stream>>>(Wq, Wk, Wv, Wb);
  transpose_kernel<<<dim3(64, 4, B_), dim3(256), 0, stream>>>(gui, inT);
  projqk_kernel<<<dim3(32, B_), dim3(128), 0, stream>>>(inT, Wb + 64 * 256, Kb);
  projv_kernel<<<dim3(32, B_, 2), dim3(128), 0, stream>>>(inT, Wb + 128 * 256, bv, VF);
  transpose_kernel<<<dim3(64, 4, B_), dim3(256), 0, stream>>>(src, inT);
  projqk_kernel<<<dim3(32, B_), dim3(128), 0, stream>>>(inT, Wb, Qb);

  attn_kernel<<<dim3(1024), dim3(256), 0, stream>>>(Qb, Kb, VF, src, gm, out);
}

// Round 12
// 198.777 us; speedup vs baseline: 1.1808x; 1.1246x over previous
//
#include <hip/hip_runtime.h>
#include <hip/hip_bf16.h>
#include <stdint.h>

// CrossAttention: B=8, C=256, H=W=64 (N=4096), CR=64.
// Pipeline (4 launches):
//   wprep:  W f32 -> Wb bf16 [384][256] (rows 0-63 Wq*log2e, 64-127 Wk, 128-383 Wv)
//   projqk: fused f32-load+LDS-transpose + MFMA; role 0: src->Qb, role 1: gui->Kb
//           (32x32-frag-linear output: per 64-px tile [sub<2][dblk<4][lane][8])
//   projv:  fused transpose + MFMA -> VF frag-linear [b][kt][half][cf<4][kblk<4][lane][8]
//   attn:   32x32x16, grid 1024 (XCD: b=bid&7), 4 waves = 2q(32) x 2ch(64);
//           no-max softmax (fast path skips -mrow sub), P in-register
//           (cvt_pk + permlane32_swap), V LDS dbuf via gll16 (0 conflicts).

#define B_ 8
#define C_ 256
#define N_ 4096
#define CR_ 64

typedef unsigned short u16;
typedef __attribute__((ext_vector_type(8))) __bf16 bf16x8;
typedef __attribute__((ext_vector_type(4))) float f32x4;
typedef __attribute__((ext_vector_type(16))) float f32x16;

__device__ __forceinline__ u16 f2bf(float f) {
  union { float f; unsigned int u; } v; v.f = f;
  unsigned int r = (v.u + 0x7fffu + ((v.u >> 16) & 1u)) >> 16;
  return (u16)r;
}
__device__ __forceinline__ unsigned int cvtpk(float a, float b) {
  unsigned int r;
  asm("v_cvt_pk_bf16_f32 %0, %1, %2" : "=v"(r) : "v"(a), "v"(b));
  return r;
}

typedef __attribute__((address_space(1))) const unsigned int gu32_t;
typedef __attribute__((address_space(3))) unsigned int lu32_t;
__device__ __forceinline__ void gll16(const void* g, void* l) {
  __builtin_amdgcn_global_load_lds((gu32_t*)g, (lu32_t*)l, 16, 0, 0);
}

// ---------------- Weight prep: EXACTLY 384 rows (64 Wq + 64 Wk + 256 Wv) ----
// grid 96 blocks x 256 thr x 4 elems = 98304 elems. (r11 bug: 80 blocks left
// Wv rows 192-255 unwritten -> replays read stale d_out bits as weights.)
__global__ __launch_bounds__(256) void wprep_kernel(
    const float* __restrict__ Wq, const float* __restrict__ Wk,
    const float* __restrict__ Wv, u16* __restrict__ Wb)
{
  const int i = (blockIdx.x * 256 + threadIdx.x) * 4;
  const int row = i >> 8;
  float4 v;
  float s = 1.0f;
  if (row < 64)       { v = *(const float4*)(Wq + i); s = 1.44269504f; }
  else if (row < 128) { v = *(const float4*)(Wk + i - 64 * 256); }
  else                { v = *(const float4*)(Wv + i - 128 * 256); }
  u16* o = Wb + i;
  o[0] = f2bf(v.x * s); o[1] = f2bf(v.y * s);
  o[2] = f2bf(v.z * s); o[3] = f2bf(v.w * s);
}

// ---------------- fused transpose helper (in-kernel): in[c][px]f32 -> Tl[px][c]bf16
// Tl stride 266 u16 (odd dword 133 -> conflict-free column access).
#define TSTR 266
#define LOAD_TILE(INP, BB, PX0) do {                                         \
    const int p4_ = (t & 15) * 4, r_ = t >> 4;                               \
    const float* ip_ = (INP) + (size_t)(BB) * C_ * N_ + (PX0) + p4_;         \
    for (int k = 0; k < 16; ++k) {                                           \
      const int c_ = r_ + k * 16;                                            \
      float4 v_ = *(const float4*)(ip_ + (size_t)c_ * N_);                   \
      Tl[(p4_ + 0) * TSTR + c_] = f2bf(v_.x);                                \
      Tl[(p4_ + 1) * TSTR + c_] = f2bf(v_.y);                                \
      Tl[(p4_ + 2) * TSTR + c_] = f2bf(v_.z);                                \
      Tl[(p4_ + 3) * TSTR + c_] = f2bf(v_.w);                                \
    }                                                                        \
  } while (0)

// ---------------- Q/K projection (fused transpose + MFMA) ------------------
// grid (64 px-tiles, B, 2 role); 256 thr = 4 waves; block = 64px x 64out.
// Output per tile tt: [sub<2][dblk<4][lane<64][8] bf16; value =
//   X[px = tt*64 + sub*32 + (lane&31)][d = dblk*16 + (lane>>5)*8 + j].
__global__ __launch_bounds__(256) void projqk_kernel(
    const float* __restrict__ src, const float* __restrict__ gui,
    const u16* __restrict__ Wb, u16* __restrict__ Qb, u16* __restrict__ Kb)
{
  __shared__ u16 Tl[64 * TSTR];  // 34,048 B (reused for output repack)
  const int t = threadIdx.x, lane = t & 63, wave = t >> 6;
  const int lg = lane >> 4, lm = lane & 15;
  const int b = blockIdx.y;
  const int role = blockIdx.z;
  const float* in = role ? gui : src;
  const u16* W64 = Wb + role * 64 * 256;
  u16* dst = role ? Kb : Qb;

  LOAD_TILE(in, b, blockIdx.x * 64);
  __syncthreads();

  // wave handles out rows mi = wave (16 ch): acc[ni<4]
  f32x4 acc[4];
  const f32x4 z4 = {0.f, 0.f, 0.f, 0.f};
#pragma unroll
  for (int i = 0; i < 4; ++i) acc[i] = z4;

  for (int ks = 0; ks < 8; ++ks) {
    bf16x8 wf = *(const bf16x8*)(W64 + (wave * 16 + lm) * C_ + ks * 32 + lg * 8);
#pragma unroll
    for (int ni = 0; ni < 4; ++ni) {
      bf16x8 pf = *(const bf16x8*)(&Tl[(ni * 16 + lm) * TSTR + ks * 32 + lg * 8]);
      acc[ni] = __builtin_amdgcn_mfma_f32_16x16x32_bf16(wf, pf, acc[ni], 0, 0, 0);
    }
  }
  __syncthreads();  // done reading input tile; reuse Tl as [64px][72] out staging

#pragma unroll
  for (int ni = 0; ni < 4; ++ni)
#pragma unroll
    for (int rp = 0; rp < 2; ++rp)
      *(unsigned int*)&Tl[(ni * 16 + lm) * 72 + wave * 16 + lg * 4 + rp * 2] =
          cvtpk(acc[ni][rp * 2], acc[ni][rp * 2 + 1]);
  __syncthreads();

  const int l31 = lane & 31, hi2 = lane >> 5;
  const int tt = b * 64 + blockIdx.x;
  u16* op = dst + (size_t)tt * 4096 + lane * 8;
#pragma unroll
  for (int fi = 0; fi < 2; ++fi) {
    const int f = wave * 2 + fi, sub = f >> 2, db = f & 3;
    *(uint4*)(op + f * 512) =
        *(const uint4*)(&Tl[(sub * 32 + l31) * 72 + db * 16 + hi2 * 8]);
  }
}

// ---------------- V projection (fused transpose + MFMA) -> VF frag-linear --
// grid (64 px-tiles, B, 2 half); 256 thr = 4 waves; wave = 32 out-ch (cf=wave).
// VF[b][kt][half][cf<4][kblk<4][lane<64][8]; value =
//   V[ch = half*128 + cf*32 + (lane&31)][key = kt*64 + kblk*16 + (lane>>5)*8 + j].
__global__ __launch_bounds__(256) void projv_kernel(
    const float* __restrict__ gui, const u16* __restrict__ Wv256,
    const float* __restrict__ bv, u16* __restrict__ VF)
{
  __shared__ u16 Tl[64 * TSTR];  // 34,048 B (reused for repack)
  const int t = threadIdx.x, lane = t & 63, wave = t >> 6;
  const int lg = lane >> 4, lm = lane & 15;
  const int b = blockIdx.y, half = blockIdx.z;

  LOAD_TILE(gui, b, blockIdx.x * 64);
  __syncthreads();

  const int chb = half * 128 + wave * 32;
  const u16* wb = Wv256 + (size_t)chb * C_;
  f32x4 acc[2][4];
  const f32x4 z4 = {0.f, 0.f, 0.f, 0.f};
#pragma unroll
  for (int i = 0; i < 2; ++i)
#pragma unroll
    for (int j = 0; j < 4; ++j) acc[i][j] = z4;

  for (int ks = 0; ks < 8; ++ks) {
    bf16x8 wf[2], pf[4];
#pragma unroll
    for (int mi = 0; mi < 2; ++mi)
      wf[mi] = *(const bf16x8*)(wb + (mi * 16 + lm) * C_ + ks * 32 + lg * 8);
#pragma unroll
    for (int ni = 0; ni < 4; ++ni)
      pf[ni] = *(const bf16x8*)(&Tl[(ni * 16 + lm) * TSTR + ks * 32 + lg * 8]);
#pragma unroll
    for (int mi = 0; mi < 2; ++mi)
#pragma unroll
      for (int ni = 0; ni < 4; ++ni)
        acc[mi][ni] = __builtin_amdgcn_mfma_f32_16x16x32_bf16(wf[mi], pf[ni], acc[mi][ni], 0, 0, 0);
  }

  f32x4 bq[2];
#pragma unroll
  for (int mi = 0; mi < 2; ++mi)
    bq[mi] = *(const f32x4*)(bv + chb + mi * 16 + lg * 4);

  __syncthreads();  // done reading input tile; reuse Tl: per-wave [32ch][72]
  u16* tw = Tl + wave * 32 * 72;
#pragma unroll
  for (int mi = 0; mi < 2; ++mi)
#pragma unroll
    for (int ni = 0; ni < 4; ++ni)
#pragma unroll
      for (int r = 0; r < 4; ++r)
        tw[(mi * 16 + lg * 4 + r) * 72 + ni * 16 + lm] = f2bf(acc[mi][ni][r] + bq[mi][r]);

  // wave-local readback -> frag emit (cf = wave)
  const int l31 = lane & 31, hi2 = lane >> 5;
  u16* vo = VF + (((size_t)(b * 64 + blockIdx.x)) * 2 + half) * 8192;
#pragma unroll
  for (int kblk = 0; kblk < 4; ++kblk)
    *(uint4*)(vo + (wave * 4 + kblk) * 512 + lane * 8) =
        *(const uint4*)(&tw[l31 * 72 + kblk * 16 + hi2 * 8]);
}

// ---------------- Flash attention (32x32, in-register P, half-staged S) ----
// LDS: Vbuf0 [0,16384), Vbuf1 [16384,32768).
#define VB1 16384

__global__ __launch_bounds__(256, 4) void attn_kernel(
    const u16* __restrict__ Qb, const u16* __restrict__ Kb, const u16* __restrict__ VF,
    const float* __restrict__ source, const float* __restrict__ gamma,
    float* __restrict__ out)
{
  __shared__ uint4 smem4[2048];  // 32768 B
  char* smem = (char*)smem4;

  const int bid = blockIdx.x;
  const int b = bid & 7;              // XCD-local batch
  const int idx = bid >> 3;
  const int qt = idx & 63;
  const int half = idx >> 6;

  const int t = threadIdx.x;
  const int lane = t & 63;
  const int wave = t >> 6;
  const int qw = wave & 1;            // 32-q slice
  const int wc = wave >> 1;           // 64-ch slice
  const int l31 = lane & 31;
  const int hi = lane >> 5;
  const int q0 = qt * 64;

  // Q frags: B-operand, col=q=l31, k=d = db*16 + hi*8 + j
  bf16x8 aq[4];
  {
    const u16* qp = Qb + ((size_t)(b * 64 + qt)) * 4096 + (qw * 4) * 512 + lane * 8;
#pragma unroll
    for (int db = 0; db < 4; ++db) aq[db] = *(const bf16x8*)(qp + db * 512);
  }

  const u16* KbT = Kb + (size_t)b * (64 * 4096);
  const char* VFb = (const char*)VF + ((size_t)(b * 128 + half)) * 16384;

  f32x16 acc[2];
#pragma unroll
  for (int c2 = 0; c2 < 2; ++c2)
#pragma unroll
    for (int r = 0; r < 16; ++r) acc[c2][r] = 0.f;
  float mrow = 0.f, lrow = 0.f;

  bf16x8 kC[8];

#define STAGEV(KTILE, VOFF) do {                                             \
    const char* vs_ = VFb + (size_t)(KTILE) * 32768 + t * 16;                \
    _Pragma("unroll")                                                        \
    for (int i = 0; i < 4; ++i)                                              \
      gll16(vs_ + i * 4096, smem + (VOFF) + wave * 1024 + i * 4096);         \
  } while (0)

#define LOADK_H(KT, H) do {                                                  \
    const u16* kp_ = KbT + (size_t)(KT) * 4096 + (H) * 2048 + lane * 8;      \
    _Pragma("unroll")                                                        \
    for (int f = 0; f < 4; ++f)                                              \
      kC[(H) * 4 + f] = *(const bf16x8*)(kp_ + f * 512);                     \
  } while (0)

// One PV pair for key-block KBLK, P packed transiently from SF (offset O8).
#define PVPAIR(SF, KBLK, O8, VCUR) do {                                      \
    unsigned uA_ = cvtpk(SF[(O8) + 0], SF[(O8) + 1]);                        \
    unsigned vA_ = cvtpk(SF[(O8) + 2], SF[(O8) + 3]);                        \
    unsigned uB_ = cvtpk(SF[(O8) + 4], SF[(O8) + 5]);                        \
    unsigned vB_ = cvtpk(SF[(O8) + 6], SF[(O8) + 7]);                        \
    asm("v_permlane32_swap_b32 %0, %1" : "+v"(uA_), "+v"(uB_));              \
    asm("v_permlane32_swap_b32 %0, %1" : "+v"(vA_), "+v"(vB_));              \
    uint4 pw_; pw_.x = uA_; pw_.y = vA_; pw_.z = uB_; pw_.w = vB_;           \
    bf16x8 pf_; __builtin_memcpy(&pf_, &pw_, 16);                            \
    __builtin_amdgcn_s_setprio(1);                                           \
    _Pragma("unroll")                                                        \
    for (int c2 = 0; c2 < 2; ++c2) {                                         \
      bf16x8 vf_ = *(const bf16x8*)(smem + (VCUR) +                          \
          (((wc * 2 + c2) * 4 + (KBLK)) << 10) + lane * 16);                 \
      acc[c2] = __builtin_amdgcn_mfma_f32_32x32x16_bf16(vf_, pf_, acc[c2], 0, 0, 0); \
    }                                                                        \
    __builtin_amdgcn_s_setprio(0);                                           \
  } while (0)

// exp pass; fast path skips the -mrow subtract (mrow==0 unless guard tripped)
#define EXPS(SF, SACC) do {                                                  \
    if (mrow == 0.f) {                                                       \
      _Pragma("unroll")                                                      \
      for (int r = 0; r < 16; ++r) {                                         \
        float e_ = __builtin_amdgcn_exp2f(SF[r]);                            \
        SF[r] = e_;                                                          \
        SACC += e_;                                                          \
      }                                                                      \
    } else {                                                                 \
      _Pragma("unroll")                                                      \
      for (int r = 0; r < 16; ++r) {                                         \
        float e_ = __builtin_amdgcn_exp2f(SF[r] - mrow);                     \
        SF[r] = e_;                                                          \
        SACC += e_;                                                          \
      }                                                                      \
    }                                                                        \
  } while (0)

// Iter T (single barrier): barrier (V(T) staged) -> stage V(T+1) -> per 32-key
// half kb: {S-MFMA(kb) -> refill kC half -> exp -> PV pair x2} -> l update.
#define ITER(KT, VCUR, VNXT) do {                                            \
    __syncthreads();                                                         \
    const int ktn_ = (KT) + 1;                                               \
    const bool pf_ = ktn_ < 64;                                              \
    if (pf_) STAGEV(ktn_, VNXT);                                             \
    float s_ = 0.f;                                                          \
    /* ---- key-half 0 ---- */                                               \
    {                                                                        \
      f32x16 sf;                                                             \
      _Pragma("unroll")                                                      \
      for (int r = 0; r < 16; ++r) sf[r] = 0.f;                              \
      __builtin_amdgcn_s_setprio(1);                                         \
      _Pragma("unroll")                                                      \
      for (int db = 0; db < 4; ++db)                                         \
        sf = __builtin_amdgcn_mfma_f32_32x32x16_bf16(kC[db], aq[db], sf, 0, 0, 0); \
      __builtin_amdgcn_s_setprio(0);                                         \
      if (pf_) LOADK_H(ktn_, 0);                                             \
      EXPS(sf, s_);                                                          \
      PVPAIR(sf, 0, 0, VCUR);                                                \
      PVPAIR(sf, 1, 8, VCUR);                                                \
    }                                                                        \
    /* ---- key-half 1 ---- */                                               \
    {                                                                        \
      f32x16 sg;                                                             \
      _Pragma("unroll")                                                      \
      for (int r = 0; r < 16; ++r) sg[r] = 0.f;                              \
      __builtin_amdgcn_s_setprio(1);                                         \
      _Pragma("unroll")                                                      \
      for (int db = 0; db < 4; ++db)                                         \
        sg = __builtin_amdgcn_mfma_f32_32x32x16_bf16(kC[4 + db], aq[db], sg, 0, 0, 0); \
      __builtin_amdgcn_s_setprio(0);                                         \
      if (pf_) LOADK_H(ktn_, 1);                                             \
      EXPS(sg, s_);                                                          \
      PVPAIR(sg, 2, 0, VCUR);                                                \
      PVPAIR(sg, 3, 8, VCUR);                                                \
    }                                                                        \
    float xs_ = s_, ys_ = s_;                                                \
    asm("v_permlane32_swap_b32 %0, %1" : "+v"(xs_), "+v"(ys_));              \
    lrow += xs_ + ys_;                                                       \
    if (lrow > 1e30f) {  /* robustness guard */                              \
      const float dsc_ = 5.421010862e-20f;  /* 2^-64 */                      \
      lrow *= dsc_; mrow += 64.f;                                            \
      _Pragma("unroll")                                                      \
      for (int c2 = 0; c2 < 2; ++c2)                                         \
        _Pragma("unroll")                                                    \
        for (int r = 0; r < 16; ++r) acc[c2][r] *= dsc_;                     \
    }                                                                        \
  } while (0)

  // prologue
  STAGEV(0, 0);
  LOADK_H(0, 0);
  LOADK_H(0, 1);
  for (int kt2 = 0; kt2 < 64; kt2 += 2) {
    ITER(kt2,     0,   VB1);
    ITER(kt2 + 1, VB1, 0);
  }
  asm volatile("s_waitcnt vmcnt(0)" ::: "memory");  // drain trailing LDS-DMA

  // ---- epilogue: D[ch][q]: ch-row = (r&3)+8*(r>>2)+4*hi, q = l31 ----
  const float inv = gamma[0] / fmaxf(lrow, 1e-37f);
#pragma unroll
  for (int c2 = 0; c2 < 2; ++c2)
#pragma unroll
    for (int r = 0; r < 16; ++r) {
      const int ch = half * 128 + wc * 64 + c2 * 32 + (r & 3) + 8 * (r >> 2) + 4 * hi;
      size_t gi = ((size_t)(b * C_ + ch)) * N_ + q0 + qw * 32 + l31;
      out[gi] = acc[c2][r] * inv + source[gi];
    }
}

extern "C" void kernel_launch(void* const* d_in, const int* in_sizes, int n_in,
                              void* d_out, int out_size, void* d_ws, size_t ws_size,
                              hipStream_t stream) {
  const float* src = (const float*)d_in[0];
  const float* gui = (const float*)d_in[1];
  const float* Wq  = (const float*)d_in[2];
  const float* Wk  = (const float*)d_in[3];
  const float* Wv  = (const float*)d_in[4];
  const float* bv  = (const float*)d_in[5];
  const float* gm  = (const float*)d_in[6];
  float* out = (float*)d_out;

  u16* Qb = (u16*)d_ws;                         // 4 MB
  u16* Kb = Qb + (size_t)B_ * N_ * CR_;         // 4 MB
  u16* VF = Kb + (size_t)B_ * N_ * CR_;         // 16 MB (ws total 24 MB)

  u16* Wb = (u16*)d_out;  // 192 KB scratch inside d_out (attn overwrites all of out)

  // 384 weight rows exactly: 96 blocks x 1024 elems = 98304 = 384*256
  wprep_kernel<<<dim3(96), dim3(256), 0, stream>>>(Wq, Wk, Wv, Wb);
  projqk_kernel<<<dim3(64, B_, 2), dim3(256), 0, stream>>>(src, gui, Wb, Qb, Kb);
  projv_kernel<<<dim3(64, B_, 2), dim3(256), 0, stream>>>(gui, Wb + 128 * 256, bv, VF);
  attn_kernel<<<dim3(1024), dim3(256), 0, stream>>>(Qb, Kb, VF, src, gm, out);
}